// Round 10
// baseline (1147.569 us; speedup 1.0000x reference)
//
#include <hip/hip_runtime.h>
#include <cfloat>
#include <cmath>

// NoisyTopKRouter eval-mode: logits = x @ W^T, top-2 + softmax over top-2.
// N=131072, D=2048, E=16. Outputs (concatenated flat in d_out as float32):
//   [0 .. 2N)   topk indices (as float values; ref dtype int64)
//   [2N .. 4N)  gating weights (softmax over the two top logits)
//
// BIT-EXACTNESS (round 7 lesson): each (row, expert) dot computed by ONE
// lane over all of D, 4 mod-4 fma chains ascending, reduced (c0+c1)+(c2+c3).
//
// g=1 mapping: lane owns ONE row and ALL 16 experts.
//   - x: lane streams its row line-by-line (8 back-to-back float4 per 128 B
//     line, MSHR-merged, fully consumed) -> HBM-exact, no LDS, no barriers.
//   - W: wave-uniform addresses into a pre-transposed W^T[D][16] (in d_ws)
//     -> compiler scalarizes to s_load (SMEM pipe), VMEM stays x-only.
//   - acc: float a4[4][16] scalars (64 VGPRs), statically indexed.
//   - epilogue: lane-local top-2 scan (ascending e, strict > => lowest index
//     wins ties, matches jax.lax.top_k) + closed-form 2-way softmax; no
//     cross-lane ops at all; stores coalesced across the wave.

constexpr int D = 2048;
constexpr int E = 16;

__global__ void wt_kernel(const float* __restrict__ W, float* __restrict__ wt) {
  const int d = blockIdx.x * blockDim.x + threadIdx.x;
  if (d >= D) return;
  #pragma unroll
  for (int e = 0; e < E; ++e)
    wt[d * E + e] = W[e * D + d];
}

__global__ __launch_bounds__(64, 2) void router_kernel(
    const float* __restrict__ x, const float* __restrict__ wt,
    float* __restrict__ out, int N) {
  const int lane = threadIdx.x;            // 0..63
  const int row  = blockIdx.x * 64 + lane;
  if (row >= N) return;

  const float4* __restrict__ xr4 = reinterpret_cast<const float4*>(x + (size_t)row * D);
  const float4* __restrict__ wt4 = reinterpret_cast<const float4*>(wt);  // [D][4] f4

  float a4[4][16];                         // a4[t][e]: chain for d === t (mod 4)
  #pragma unroll
  for (int t = 0; t < 4; ++t)
    #pragma unroll
    for (int e = 0; e < E; ++e) a4[t][e] = 0.f;

  #pragma unroll 1
  for (int c = 0; c < D / 32; ++c) {       // one 128 B line of the row per iter
    float4 xv[8];
    #pragma unroll
    for (int j = 0; j < 8; ++j) xv[j] = xr4[c * 8 + j];
    #pragma unroll
    for (int j = 0; j < 8; ++j) {
      #pragma unroll
      for (int t = 0; t < 4; ++t) {        // d = c*32 + j*4 + t
        const float xd = (t == 0) ? xv[j].x
                       : (t == 1) ? xv[j].y
                       : (t == 2) ? xv[j].z : xv[j].w;
        const int dtt = c * 32 + j * 4 + t;
        #pragma unroll
        for (int eq = 0; eq < 4; ++eq) {   // experts 4eq .. 4eq+3
          const float4 wv = wt4[dtt * 4 + eq];   // wave-uniform -> s_load
          a4[t][eq * 4 + 0] = fmaf(xd, wv.x, a4[t][eq * 4 + 0]);
          a4[t][eq * 4 + 1] = fmaf(xd, wv.y, a4[t][eq * 4 + 1]);
          a4[t][eq * 4 + 2] = fmaf(xd, wv.z, a4[t][eq * 4 + 2]);
          a4[t][eq * 4 + 3] = fmaf(xd, wv.w, a4[t][eq * 4 + 3]);
        }
      }
    }
  }

  // ---- lane-local top-2 over all 16 experts (proven scan, round 9) ----
  float m1 = -FLT_MAX, m2 = -FLT_MAX;
  int   i1 = E, i2 = E;
  #pragma unroll
  for (int e = 0; e < E; ++e) {
    // horizontal sum in the proven order
    const float v = (a4[0][e] + a4[1][e]) + (a4[2][e] + a4[3][e]);
    const bool gt1 = v > m1;
    const bool gt2 = v > m2;
    m2 = gt1 ? m1 : (gt2 ? v : m2);
    i2 = gt1 ? i1 : (gt2 ? e : i2);
    m1 = gt1 ? v : m1;
    i1 = gt1 ? e : i1;
  }

  const float ex  = expf(m2 - m1);         // m2 <= m1 -> ex in (0,1]
  const float inv = 1.0f / (1.0f + ex);
  float2* outi = reinterpret_cast<float2*>(out);
  float2* outw = reinterpret_cast<float2*>(out + (size_t)N * 2);
  outi[row] = make_float2((float)i1, (float)i2);
  outw[row] = make_float2(inv, ex * inv);
}

extern "C" void kernel_launch(void* const* d_in, const int* in_sizes, int n_in,
                              void* d_out, int out_size, void* d_ws, size_t ws_size,
                              hipStream_t stream) {
  const float* x = (const float*)d_in[0];
  const float* W = (const float*)d_in[1];
  float* out = (float*)d_out;
  float* wt  = (float*)d_ws;               // W^T staging: D*E*4 = 128 KB
  const int N = in_sizes[0] / D;           // 131072

  wt_kernel<<<D / 256, 256, 0, stream>>>(W, wt);
  router_kernel<<<N / 64, 64, 0, stream>>>(x, wt, out, N);
}

// Round 11
// 567.963 us; speedup vs baseline: 2.0205x; 2.0205x over previous
//
#include <hip/hip_runtime.h>
#include <cfloat>
#include <cmath>

// NoisyTopKRouter eval-mode: logits = x @ W^T, top-2 + softmax over top-2.
// N=131072, D=2048, E=16. Outputs (concatenated flat in d_out as float32):
//   [0 .. 2N)   topk indices (as float values; ref dtype int64)
//   [2N .. 4N)  gating weights (softmax over the two top logits)
//
// BIT-EXACTNESS (round 7): each (row, expert) dot computed by ONE lane over
// all of D, 4 mod-4 fma chains ascending, reduced (c0+c1)+(c2+c3).
//
// Design (lessons r8/r9/r10): lane owns 1 row x all 16 experts.
//  - x: global->LDS via global_load_lds, 8 rows x 128 B per 1 KB instruction
//    (perfectly coalesced). LDS slot swizzle jj = j ^ (row&7) is applied by
//    PRE-SWIZZLING the per-lane GLOBAL address (LDS dest stays linear);
//    reads then hit the conflict-free contiguous-b128 bank pattern.
//  - Each row is read from LDS by exactly ONE lane -> DS pipe ~49k cy/CU.
//  - W: pre-transposed wt[D][16] (d_ws); phase offset pinned uniform via
//    readfirstlane -> s_load on the SMEM pipe; VMEM carries only x.
//  - Wave-private slabs, double-buffered, NO barriers; per-wave counted
//    s_waitcnt vmcnt(8) (stage(p) landed; stage(p+1) still in flight).

constexpr int D = 2048;
constexpr int E = 16;
constexpr int BLOCK = 256;          // 4 waves
constexpr int RPW = 64;             // rows per wave (1 per lane)
constexpr int RB = 256;             // rows per block
constexpr int PW = 32;              // floats of D per phase
constexpr int NP = D / PW;          // 64 phases
constexpr int SLABF = RPW * PW;     // 2048 floats = 8 KB per wave-slab

__global__ void wt_kernel(const float* __restrict__ W, float* __restrict__ wt) {
  const int d = blockIdx.x * blockDim.x + threadIdx.x;
  if (d >= D) return;
  #pragma unroll
  for (int e = 0; e < E; ++e) wt[d * E + e] = W[e * D + d];
}

__global__ __launch_bounds__(BLOCK, 2) void router_kernel(
    const float* __restrict__ x, const float* __restrict__ wt,
    float* __restrict__ out, int N) {
  __shared__ float xs[2][4][SLABF];   // 64 KB -> 2 blocks/CU

  const int tid  = threadIdx.x;
  const int lane = tid & 63;
  const int wid  = tid >> 6;          // 0..3
  const int rr   = lane >> 3;         // staging: row within 8-row group
  const int jj   = lane & 7;          // staging: stored slot
  const int rx   = lane & 7;          // read: this row's swizzle key
  const int waverow = blockIdx.x * RB + wid * RPW;
  const int row  = waverow + lane;    // the row this lane owns
  if (waverow >= N) return;

  // staging source: instr k stages rows waverow+8k..+8k+7; lane (rr,jj)
  // supplies row (waverow+8k+rr), d-offset p*32 + 4*(jj ^ rr). The jj^rr
  // permutation within each 8-lane cluster keeps the cluster covering one
  // full 128 B line -> perfectly coalesced despite the swizzle.
  const float* gsb = x + (size_t)(waverow + rr) * D + 4 * (jj ^ rr);

  auto stage = [&](int p, int buf) {
    const float* g = gsb + p * PW;
    float* ld = &xs[buf][wid][0];     // wave-uniform dest base
    #pragma unroll
    for (int k = 0; k < 8; ++k)
      __builtin_amdgcn_global_load_lds(
          (const __attribute__((address_space(1))) void*)(g + (size_t)(8 * k) * D),
          (__attribute__((address_space(3))) void*)(ld + k * 256), 16, 0, 0);
  };

  float a4[4][E];                     // a4[t][e]: chain for d === t (mod 4)
  #pragma unroll
  for (int t = 0; t < 4; ++t)
    #pragma unroll
    for (int e = 0; e < E; ++e) a4[t][e] = 0.f;

  stage(0, 0);

  #pragma unroll 1
  for (int p = 0; p < NP; ++p) {
    const int cur = p & 1;
    if (p + 1 < NP) {
      stage(p + 1, cur ^ 1);
      // stage(p) [8 oldest] retired; stage(p+1) [8] still in flight
      asm volatile("s_waitcnt vmcnt(8)" ::: "memory");
    } else {
      asm volatile("s_waitcnt vmcnt(0)" ::: "memory");
    }
    __builtin_amdgcn_sched_barrier(0);

    // lane's row slice for this phase: 8 float4 at swizzled slots
    const float* ls = &xs[cur][wid][lane * PW];
    float4 xv[8];
    #pragma unroll
    for (int j = 0; j < 8; ++j)
      xv[j] = *reinterpret_cast<const float4*>(ls + 4 * (j ^ rx));

    // W for this phase: uniform offset pinned to SGPR -> s_load path
    const int wo = __builtin_amdgcn_readfirstlane(p * (PW * E));
    const float4* __restrict__ wp4 = reinterpret_cast<const float4*>(wt + wo);

    #pragma unroll
    for (int j = 0; j < 8; ++j) {
      #pragma unroll
      for (int t = 0; t < 4; ++t) {   // d = p*32 + 4j + t
        const float xd = (t == 0) ? xv[j].x
                       : (t == 1) ? xv[j].y
                       : (t == 2) ? xv[j].z : xv[j].w;
        #pragma unroll
        for (int eq = 0; eq < 4; ++eq) {
          const float4 wv = wp4[(4 * j + t) * 4 + eq];
          a4[t][eq * 4 + 0] = fmaf(xd, wv.x, a4[t][eq * 4 + 0]);
          a4[t][eq * 4 + 1] = fmaf(xd, wv.y, a4[t][eq * 4 + 1]);
          a4[t][eq * 4 + 2] = fmaf(xd, wv.z, a4[t][eq * 4 + 2]);
          a4[t][eq * 4 + 3] = fmaf(xd, wv.w, a4[t][eq * 4 + 3]);
        }
      }
    }
  }

  // ---- lane-local top-2 over all 16 experts (proven scan, rounds 9-10:
  //      ascending e, strict > => lowest index wins ties) ----
  float m1 = -FLT_MAX, m2 = -FLT_MAX;
  int   i1 = E, i2 = E;
  #pragma unroll
  for (int e = 0; e < E; ++e) {
    // horizontal sum in the proven order
    const float v = (a4[0][e] + a4[1][e]) + (a4[2][e] + a4[3][e]);
    const bool gt1 = v > m1;
    const bool gt2 = v > m2;
    m2 = gt1 ? m1 : (gt2 ? v : m2);
    i2 = gt1 ? i1 : (gt2 ? e : i2);
    m1 = gt1 ? v : m1;
    i1 = gt1 ? e : i1;
  }

  const float ex  = expf(m2 - m1);        // m2 <= m1 -> ex in (0,1]
  const float inv = 1.0f / (1.0f + ex);
  float2* outi = reinterpret_cast<float2*>(out);
  float2* outw = reinterpret_cast<float2*>(out + (size_t)N * 2);
  outi[row] = make_float2((float)i1, (float)i2);
  outw[row] = make_float2(inv, ex * inv);
}

extern "C" void kernel_launch(void* const* d_in, const int* in_sizes, int n_in,
                              void* d_out, int out_size, void* d_ws, size_t ws_size,
                              hipStream_t stream) {
  const float* x = (const float*)d_in[0];
  const float* W = (const float*)d_in[1];
  float* out = (float*)d_out;
  float* wt  = (float*)d_ws;               // W^T staging: D*E*4 = 128 KB
  const int N = in_sizes[0] / D;           // 131072

  wt_kernel<<<D / 256, 256, 0, stream>>>(W, wt);
  router_kernel<<<N / RB, BLOCK, 0, stream>>>(x, wt, out, N);
}

// Round 13
// 566.371 us; speedup vs baseline: 2.0262x; 1.0028x over previous
//
#include <hip/hip_runtime.h>
#include <cfloat>
#include <cmath>

// NoisyTopKRouter eval-mode: logits = x @ W^T, top-2 + softmax over top-2.
// N=131072, D=2048, E=16. Outputs (concatenated flat in d_out as float32):
//   [0 .. 2N)   topk indices (as float values; ref dtype int64)
//   [2N .. 4N)  gating weights (softmax over the two top logits)
//
// BIT-EXACTNESS (round 7): each (row, expert) dot computed by ONE lane over
// all of D, 4 mod-4 fma chains ascending, reduced (c0+c1)+(c2+c3).
//
// g=1 mapping: lane owns 1 row x all 16 experts. Three pipes, three jobs:
//  - x (HBM stream): global->LDS via global_load_lds, double-buffered,
//    wave-private slabs, NO barriers, counted s_waitcnt vmcnt(9).
//    LDS layout: per-lane slice of PITCH=36 floats (36/4=9 odd -> read quad
//    (lane+b)%8 walks all 8 bank-quads = conflict-free, fixing round 11's
//    all-lanes-on-quad-0 pileup). Staged by 9 instrs/phase via the bijection
//    64k+lane = 9r+j (j==8 -> pad slot, sourced from the same 128B line).
//  - W (uniform operand): pre-transposed wt[D][16] read through an
//    address_space(4) "constant" pointer at wave-uniform offsets -> s_load
//    on the scalar pipe, consumed as SGPR operands by v_fmac. AS(4) loads
//    use clang ext_vector_type (HIP float4's member operator= cannot bind
//    an AS(4) reference -- round 12 compile failure).
//  - VALU: 16 fma per x-float; ~131k cy/SIMD vs 420k cy HBM/CU -> HBM-bound.

constexpr int D = 2048;
constexpr int E = 16;
constexpr int BLOCK = 256;          // 4 waves
constexpr int RB = 256;             // rows per block (64 per wave, 1 per lane)
constexpr int PW = 32;              // floats of D per phase
constexpr int NP = D / PW;          // 64 phases
constexpr int PITCH = 36;           // floats per lane slice (9 f4, odd)
constexpr int SLABF = 64 * PITCH;   // 2304 floats = 9216 B per wave-buffer

typedef __attribute__((ext_vector_type(4))) float f32x4;

__global__ void wt_kernel(const float* __restrict__ W, float* __restrict__ wt) {
  const int d = blockIdx.x * blockDim.x + threadIdx.x;
  if (d >= D) return;
  #pragma unroll
  for (int e = 0; e < E; ++e) wt[d * E + e] = W[e * D + d];
}

__global__ __launch_bounds__(BLOCK, 2) void router_kernel(
    const float* __restrict__ x, const float* __restrict__ wt,
    float* __restrict__ out, int N) {
  __shared__ float xs[2][4][SLABF];   // 73728 B -> 2 blocks/CU, 8 waves/CU

  const int tid  = threadIdx.x;
  const int lane = tid & 63;
  const int wid  = tid >> 6;          // 0..3
  const int waverow = blockIdx.x * RB + wid * 64;
  const int row  = waverow + lane;    // the row this lane owns
  if (waverow >= N) return;

  // staging decode: instr k, lane l -> v = 64k+l = 9r+j; stage row r's j-th
  // f4 of the phase slice into linear LDS float offset v*4 (== r*36 + 4j).
  // j==8 is the pitch pad: source row r's j=7 chunk (same 128 B line, free).
  int soff[9];
  #pragma unroll
  for (int k = 0; k < 9; ++k) {
    const int v = 64 * k + lane;
    const int r = v / 9;
    const int j = v - 9 * r;
    const int jj = (j < 8) ? j : 7;
    soff[k] = r * D + 4 * jj;         // + p*PW at stage time
  }
  const float* gx = x + (size_t)waverow * D;

  auto stage = [&](int p, int buf) {
    float* ld = &xs[buf][wid][0];     // wave-uniform dest base
    #pragma unroll
    for (int k = 0; k < 9; ++k)
      __builtin_amdgcn_global_load_lds(
          (const __attribute__((address_space(1))) void*)(gx + soff[k] + p * PW),
          (__attribute__((address_space(3))) void*)(ld + k * 256), 16, 0, 0);
  };

  // W through the constant address space: uniform address -> s_load
  const __attribute__((address_space(4))) f32x4* cw4 =
      (const __attribute__((address_space(4))) f32x4*)wt;

  float a4[4][E];                     // a4[t][e]: chain for d === t (mod 4)
  #pragma unroll
  for (int t = 0; t < 4; ++t)
    #pragma unroll
    for (int e = 0; e < E; ++e) a4[t][e] = 0.f;

  stage(0, 0);

  #pragma unroll 1
  for (int p = 0; p < NP; ++p) {
    const int cur = p & 1;
    if (p + 1 < NP) {
      stage(p + 1, cur ^ 1);
      // stage(p) [9 oldest] retired; stage(p+1) [9] still in flight.
      // s_load/ds_read are lgkm ops and do not perturb the vm count.
      asm volatile("s_waitcnt vmcnt(9)" ::: "memory");
    } else {
      asm volatile("s_waitcnt vmcnt(0)" ::: "memory");
    }
    __builtin_amdgcn_sched_barrier(0);

    const float* ls = &xs[cur][wid][lane * PITCH];
    const int wb = p * 128;           // f4 index of this phase's W block

    #pragma unroll
    for (int g4 = 0; g4 < 8; ++g4) {  // d-quad: d = p*32 + 4*g4 + t
      const float4 xq = *reinterpret_cast<const float4*>(ls + 4 * g4);
      // t = 0,1 half: 8 f4 of W (32 floats; fits SGPRs, and fits VGPR
      // budget even in the scalarization-failure fallback)
      {
        f32x4 w[8];
        #pragma unroll
        for (int i = 0; i < 8; ++i) w[i] = cw4[wb + g4 * 16 + i];
        #pragma unroll
        for (int eq = 0; eq < 4; ++eq) {
          a4[0][eq*4+0] = fmaf(xq.x, w[eq].x, a4[0][eq*4+0]);
          a4[0][eq*4+1] = fmaf(xq.x, w[eq].y, a4[0][eq*4+1]);
          a4[0][eq*4+2] = fmaf(xq.x, w[eq].z, a4[0][eq*4+2]);
          a4[0][eq*4+3] = fmaf(xq.x, w[eq].w, a4[0][eq*4+3]);
        }
        #pragma unroll
        for (int eq = 0; eq < 4; ++eq) {
          a4[1][eq*4+0] = fmaf(xq.y, w[4+eq].x, a4[1][eq*4+0]);
          a4[1][eq*4+1] = fmaf(xq.y, w[4+eq].y, a4[1][eq*4+1]);
          a4[1][eq*4+2] = fmaf(xq.y, w[4+eq].z, a4[1][eq*4+2]);
          a4[1][eq*4+3] = fmaf(xq.y, w[4+eq].w, a4[1][eq*4+3]);
        }
      }
      // t = 2,3 half
      {
        f32x4 w[8];
        #pragma unroll
        for (int i = 0; i < 8; ++i) w[i] = cw4[wb + g4 * 16 + 8 + i];
        #pragma unroll
        for (int eq = 0; eq < 4; ++eq) {
          a4[2][eq*4+0] = fmaf(xq.z, w[eq].x, a4[2][eq*4+0]);
          a4[2][eq*4+1] = fmaf(xq.z, w[eq].y, a4[2][eq*4+1]);
          a4[2][eq*4+2] = fmaf(xq.z, w[eq].z, a4[2][eq*4+2]);
          a4[2][eq*4+3] = fmaf(xq.z, w[eq].w, a4[2][eq*4+3]);
        }
        #pragma unroll
        for (int eq = 0; eq < 4; ++eq) {
          a4[3][eq*4+0] = fmaf(xq.w, w[4+eq].x, a4[3][eq*4+0]);
          a4[3][eq*4+1] = fmaf(xq.w, w[4+eq].y, a4[3][eq*4+1]);
          a4[3][eq*4+2] = fmaf(xq.w, w[4+eq].z, a4[3][eq*4+2]);
          a4[3][eq*4+3] = fmaf(xq.w, w[4+eq].w, a4[3][eq*4+3]);
        }
      }
    }
  }

  // ---- lane-local top-2 over all 16 experts (proven scan, rounds 9-11:
  //      ascending e, strict > => lowest index wins ties) ----
  float m1 = -FLT_MAX, m2 = -FLT_MAX;
  int   i1 = E, i2 = E;
  #pragma unroll
  for (int e = 0; e < E; ++e) {
    // horizontal sum in the proven order
    const float v = (a4[0][e] + a4[1][e]) + (a4[2][e] + a4[3][e]);
    const bool gt1 = v > m1;
    const bool gt2 = v > m2;
    m2 = gt1 ? m1 : (gt2 ? v : m2);
    i2 = gt1 ? i1 : (gt2 ? e : i2);
    m1 = gt1 ? v : m1;
    i1 = gt1 ? e : i1;
  }

  const float ex  = expf(m2 - m1);        // m2 <= m1 -> ex in (0,1]
  const float inv = 1.0f / (1.0f + ex);
  float2* outi = reinterpret_cast<float2*>(out);
  float2* outw = reinterpret_cast<float2*>(out + (size_t)N * 2);
  outi[row] = make_float2((float)i1, (float)i2);
  outw[row] = make_float2(inv, ex * inv);
}

extern "C" void kernel_launch(void* const* d_in, const int* in_sizes, int n_in,
                              void* d_out, int out_size, void* d_ws, size_t ws_size,
                              hipStream_t stream) {
  const float* x = (const float*)d_in[0];
  const float* W = (const float*)d_in[1];
  float* out = (float*)d_out;
  float* wt  = (float*)d_ws;               // W^T staging: D*E*4 = 128 KB
  const int N = in_sizes[0] / D;           // 131072

  wt_kernel<<<D / 256, 256, 0, stream>>>(W, wt);
  router_kernel<<<N / RB, BLOCK, 0, stream>>>(x, wt, out, N);
}